// Round 8
// baseline (27096.094 us; speedup 1.0000x reference)
//
#include <hip/hip_runtime.h>
#include <cstdint>
#include <cstddef>

// ---------------- problem constants ----------------
#define TSTEPS 2000
#define NB     256      // batch
#define HID    128
#define CIN    14
#define NGRP   128      // 2-row groups
#define RG     2

// ---------------- workspace layout (bytes) ----------------
#define OFF_FLG  0ull                      // [128 g][4 q] * 32B = 16384
#define OFF_M1   16384ull                  // [2][128][2r][128h] f32 = 262144
#define OFF_M2   (OFF_M1 + 262144ull)      // [2][128][2r][128h] f32
#define OFF_SPK  (OFF_M2 + 262144ull)      // [2][128][8w] u32 = 8192
#define OFF_FEAT (OFF_SPK + 8192ull)       // [256][128] f32 = 131072
#define OFF_AB   (OFF_FEAT + 131072ull)    // a[64], b[64] = 512
#define OFF_PART (OFF_AB + 512ull)         // [2304][64][2] f32 = 1179648
#define OFF_MASK (OFF_PART + 1179648ull)   // [2000][256] u64 = 4096000
#define ZERO_WORDS 137216                  // flags + m1 + m2 + spk

// ============================================================
// K0: zero flags + state buffers (every launch, for graph replay)
// ============================================================
__global__ __launch_bounds__(256) void k0_zero(unsigned* ws) {
  int i = blockIdx.x * 256 + threadIdx.x;
  if (i < ZERO_WORDS) ws[i] = 0u;
}

// ============================================================
// K1: conv1d -> per-(b,tile) partial sum/sumsq for BN
// ============================================================
__global__ __launch_bounds__(256) void k1_stats(const float* __restrict__ x,
                                                const float* __restrict__ cw,
                                                float* __restrict__ part) {
  __shared__ float xLds[244 * CIN];
  __shared__ float cwLds[64 * 70];
  __shared__ float red[2][4][64];
  const int b = blockIdx.x, tile = blockIdx.y;
  const int base = tile * 240;
  for (int f = threadIdx.x; f < 244 * CIN; f += 256) {
    int u = f / CIN, ci = f - u * CIN;
    int tp = base + u - 2;
    xLds[f] = (tp >= 0 && tp < TSTEPS) ? x[((size_t)tp * NB + b) * CIN + ci] : 0.0f;
  }
  for (int f = threadIdx.x; f < 64 * 70; f += 256) cwLds[f] = cw[f];
  __syncthreads();

  const int co = threadIdx.x & 63, tq = threadIdx.x >> 6;
  float cwr[70];
#pragma unroll
  for (int s = 0; s < 70; ++s) cwr[s] = cwLds[co * 70 + s];
  float xw[5][CIN];
  const int u0 = tq * 60;
#pragma unroll
  for (int r = 0; r < 4; ++r)
#pragma unroll
    for (int ci = 0; ci < CIN; ++ci) xw[r][ci] = xLds[(u0 + r) * CIN + ci];

  float s1 = 0.0f, s2 = 0.0f;
  const int tbase = base + tq * 60;
  for (int i5 = 0; i5 < 60; i5 += 5) {
#pragma unroll
    for (int s = 0; s < 5; ++s) {
#pragma unroll
      for (int ci = 0; ci < CIN; ++ci)
        xw[(s + 4) % 5][ci] = xLds[(u0 + i5 + s + 4) * CIN + ci];
      float y = 0.0f;
#pragma unroll
      for (int kk = 0; kk < 5; ++kk)
#pragma unroll
        for (int ci = 0; ci < CIN; ++ci)
          y += xw[(s + kk) % 5][ci] * cwr[ci * 5 + kk];
      if (tbase + i5 + s < TSTEPS) { s1 += y; s2 += y * y; }
    }
  }
  red[0][tq][co] = s1; red[1][tq][co] = s2;
  __syncthreads();
  if (threadIdx.x < 64) {
    float a1 = red[0][0][co] + red[0][1][co] + red[0][2][co] + red[0][3][co];
    float a2 = red[1][0][co] + red[1][1][co] + red[1][2][co] + red[1][3][co];
    int blk = tile * NB + b;
    part[blk * 128 + co * 2 + 0] = a1;
    part[blk * 128 + co * 2 + 1] = a2;
  }
}

// K1b: deterministic fixed-order reduction of partials -> a[co], b[co]
__global__ __launch_bounds__(256) void k1b_reduce(const float* __restrict__ gamma,
                           const float* __restrict__ beta,
                           const float* __restrict__ part, float* __restrict__ ab) {
  __shared__ float red[2][4][64];
  const int co = threadIdx.x & 63, pt = threadIdx.x >> 6;
  float s1 = 0.0f, s2 = 0.0f;
  for (int blk = pt * 576; blk < pt * 576 + 576; ++blk) {
    s1 += part[blk * 128 + co * 2 + 0];
    s2 += part[blk * 128 + co * 2 + 1];
  }
  red[0][pt][co] = s1; red[1][pt][co] = s2;
  __syncthreads();
  if (threadIdx.x < 64) {
    float a1 = red[0][0][co] + red[0][1][co] + red[0][2][co] + red[0][3][co];
    float a2 = red[1][0][co] + red[1][1][co] + red[1][2][co] + red[1][3][co];
    const float N = (float)TSTEPS * (float)NB;
    float mu = a1 / N;
    float var = a2 / N - mu * mu;
    float rstd = 1.0f / sqrtf(var + 1e-5f);
    float a = gamma[co] * rstd;
    ab[co] = a;
    ab[64 + co] = beta[co] - mu * a;
  }
}

// ============================================================
// K2: conv1d -> BN -> spike -> pack 64 channel bits into u64 per (t,b)
// ============================================================
__global__ __launch_bounds__(256) void k2_spike(const float* __restrict__ x,
                                                const float* __restrict__ cw,
                                                const float* __restrict__ thrp,
                                                const float* __restrict__ ab,
                                                unsigned long long* __restrict__ masks) {
  __shared__ float xLds[244 * CIN];
  __shared__ float cwLds[64 * 70];
  const int b = blockIdx.x, tile = blockIdx.y;
  const int base = tile * 240;
  for (int f = threadIdx.x; f < 244 * CIN; f += 256) {
    int u = f / CIN, ci = f - u * CIN;
    int tp = base + u - 2;
    xLds[f] = (tp >= 0 && tp < TSTEPS) ? x[((size_t)tp * NB + b) * CIN + ci] : 0.0f;
  }
  for (int f = threadIdx.x; f < 64 * 70; f += 256) cwLds[f] = cw[f];
  __syncthreads();

  const int co = threadIdx.x & 63, tq = threadIdx.x >> 6;
  const float thr = thrp[0];
  const float aC = ab[co], bC = ab[64 + co];
  float cwr[70];
#pragma unroll
  for (int s = 0; s < 70; ++s) cwr[s] = cwLds[co * 70 + s];
  float xw[5][CIN];
  const int u0 = tq * 60;
#pragma unroll
  for (int r = 0; r < 4; ++r)
#pragma unroll
    for (int ci = 0; ci < CIN; ++ci) xw[r][ci] = xLds[(u0 + r) * CIN + ci];

  const int tbase = base + tq * 60;
  for (int i5 = 0; i5 < 60; i5 += 5) {
#pragma unroll
    for (int s = 0; s < 5; ++s) {
#pragma unroll
      for (int ci = 0; ci < CIN; ++ci)
        xw[(s + 4) % 5][ci] = xLds[(u0 + i5 + s + 4) * CIN + ci];
      float y = 0.0f;
#pragma unroll
      for (int kk = 0; kk < 5; ++kk)
#pragma unroll
        for (int ci = 0; ci < CIN; ++ci)
          y += xw[(s + kk) % 5][ci] * cwr[ci * 5 + kk];
      int t = tbase + i5 + s;
      if (t < TSTEPS) {
        float bn = y * aC + bC;
        unsigned long long m = __ballot(bn - thr > 0.0f);  // lane i = channel i
        if (co == 0) masks[(size_t)t * NB + b] = m;
      }
    }
  }
}

// ============================================================
// KP: persistent two-layer SLSTM, TWO-GROUP INTERLEAVE.
// Block = h-quarter q (bid>>6) x group pair {gA,gB} = {2*(bid&63), +1}.
// The 4 blocks sharing (bid&63) form a closed clique serving both groups.
// Per phase: compute A (L1 step p + L2 step p-1), flag, poll A(p+1),
// ISSUE A(p+1) loads; compute B, flag, poll B(p+1), ISSUE B(p+1).
// Each role's stage-load latency hides under the OTHER role's compute.
// Same weights serve both roles (same h-quarter). Fence-free relaxed-agent
// atomics; __syncthreads drains vmcnt before flags.
// ============================================================
__device__ __forceinline__ float sigm(float v) { return 1.0f / (1.0f + expf(-v)); }

__device__ __forceinline__ void do_gemms(const float* A1x, const float* A2x,
    float* g1x, float* g2x,
    const float wr1[2][2][12], const float wr2[2][2][16],
    int kq, int j0) {
  float a100 = 0, a101 = 0, a110 = 0, a111 = 0;
  const float4* v1 = (const float4*)A1x;
#pragma unroll
  for (int m = 0; m < 12; ++m) {
    float4 av = v1[m * 8 + kq];
    a100 += wr1[0][0][m] * av.x; a101 += wr1[0][0][m] * av.y;
    a110 += wr1[1][0][m] * av.x; a111 += wr1[1][0][m] * av.y;
    a100 += wr1[0][1][m] * av.z; a101 += wr1[0][1][m] * av.w;
    a110 += wr1[1][1][m] * av.z; a111 += wr1[1][1][m] * av.w;
  }
  float a200 = 0, a201 = 0, a210 = 0, a211 = 0;
  const float4* v2 = (const float4*)A2x;
#pragma unroll
  for (int m = 0; m < 16; ++m) {
    float4 av = v2[m * 8 + kq];
    a200 += wr2[0][0][m] * av.x; a201 += wr2[0][0][m] * av.y;
    a210 += wr2[1][0][m] * av.x; a211 += wr2[1][0][m] * av.y;
    a200 += wr2[0][1][m] * av.z; a201 += wr2[0][1][m] * av.w;
    a210 += wr2[1][1][m] * av.z; a211 += wr2[1][1][m] * av.w;
  }
#define RED3(v) v += __shfl_xor(v, 8); v += __shfl_xor(v, 16); v += __shfl_xor(v, 32)
  RED3(a100); RED3(a101); RED3(a110); RED3(a111);
  RED3(a200); RED3(a201); RED3(a210); RED3(a211);
#undef RED3
  if (kq == 0) {
    *(float4*)&g1x[j0 * 2] = make_float4(a100, a101, a110, a111);
    *(float4*)&g2x[j0 * 2] = make_float4(a200, a201, a210, a211);
  }
}

__global__ __launch_bounds__(512) void kp_fused(char* ws,
    const float* __restrict__ w_ih1, const float* __restrict__ w_hh1,
    const float* __restrict__ b_ih1, const float* __restrict__ b_hh1,
    const float* __restrict__ thr1p,
    const float* __restrict__ w_ih2, const float* __restrict__ w_hh2,
    const float* __restrict__ b_ih2, const float* __restrict__ b_hh2,
    const float* __restrict__ thr2p) {
  // A layout: entry f = k*2 + r  (float4 = 2k x 2r); per-wave GEMM read =
  // 8 kq x 16B contiguous broadcast -> conflict-free.
  __shared__ __align__(16) float A1a[384], A1b[384];   // [192k][2r]
  __shared__ __align__(16) float A2a[512], A2b[512];   // [256k][2r]
  __shared__ __align__(16) float g1a[256], g2a[256], g1b[256], g2b[256];
  __shared__ float bias1[128], bias2[128];

  const int tid = threadIdx.x;
  const int bid = blockIdx.x;
  const int q = bid >> 6;                 // h-quarter
  const int gA = (bid & 63) * 2, gB = gA + 1;
  const int lane = tid & 63, wv = tid >> 6;
  const int u = lane & 7, kq = lane >> 3; // 8-way k-pair split
  const int jp = wv * 8 + u;              // 0..63 -> 2 gate rows each
  const int j0 = jp * 2;

  unsigned* flags = (unsigned*)(ws + OFF_FLG);
  float* m1ws = (float*)(ws + OFF_M1);
  float* m2ws = (float*)(ws + OFF_M2);
  unsigned* spkw = (unsigned*)(ws + OFF_SPK);
  float* feat = (float*)(ws + OFF_FEAT);
  const unsigned long long* masks = (const unsigned long long*)(ws + OFF_MASK);

  // ---- one-time: weights -> registers; k = (m*8+kq)*2 + kk ----
  float wr1[2][2][12], wr2[2][2][16];
#pragma unroll
  for (int jj = 0; jj < 2; ++jj) {
    const int j = j0 + jj;
    const int a = j >> 5, hl = j & 31;
    const int grow = a * 128 + q * 32 + hl;
#pragma unroll
    for (int m = 0; m < 12; ++m)
#pragma unroll
      for (int kk = 0; kk < 2; ++kk) {
        int k = (m * 8 + kq) * 2 + kk;
        wr1[jj][kk][m] = (k < 64) ? w_ih1[grow * 64 + k]
                                  : w_hh1[grow * 128 + (k - 64)];
      }
#pragma unroll
    for (int m = 0; m < 16; ++m)
#pragma unroll
      for (int kk = 0; kk < 2; ++kk) {
        int k = (m * 8 + kq) * 2 + kk;
        wr2[jj][kk][m] = (k < 128) ? w_ih2[grow * 128 + k]
                                   : w_hh2[grow * 128 + (k - 128)];
      }
  }
  if (tid < 128) {
    int a = tid >> 5, hl = tid & 31;
    int gr = a * 128 + q * 32 + hl;
    bias1[tid] = b_ih1[gr] + b_hh1[gr];
    bias2[tid] = b_ih2[gr] + b_hh2[gr];
  }
  const float thr1 = thr1p[0], thr2 = thr2p[0];
  float sy1a = 0, me1a = 0, sy2a = 0, me2a = 0, fca = 0;
  float sy1b = 0, me1b = 0, sy2b = 0, me2b = 0, fcb = 0;
  float sm1a = 0, sm2a = 0, sm1b = 0, sm2b = 0;
  unsigned sspa = 0, sspb = 0;
  unsigned long long mka = 0, mkb = 0;
  __syncthreads();

// ---- staging macros ----
#define ISSUE(gX, pp, sm1, sm2, ssp, smk)                                      \
  {                                                                            \
    const int par = ((pp) + 1) & 1;                                            \
    const int wpar = (pp) & 1;                                                 \
    if (tid < 128) {                                                           \
      int tmask = ((pp) < TSTEPS) ? (pp) : (TSTEPS - 1);                       \
      smk = masks[(size_t)tmask * NB + (gX) * 2 + (tid & 1)];                  \
    }                                                                          \
    if (tid >= 128 && tid < 384)                                               \
      sm1 = __hip_atomic_load(                                                 \
          &m1ws[((size_t)(par * 128 + (gX)) * 2 + (tid & 1)) * 128 +           \
                ((tid >> 1) - 64)],                                            \
          __ATOMIC_RELAXED, __HIP_MEMORY_SCOPE_AGENT);                         \
    if (tid < 256)                                                             \
      ssp = __hip_atomic_load(                                                 \
          &spkw[(size_t)(par * 128 + (gX)) * 8 + (tid & 1) * 4 +               \
                ((tid >> 1) >> 5)],                                            \
          __ATOMIC_RELAXED, __HIP_MEMORY_SCOPE_AGENT);                         \
    else                                                                       \
      sm2 = __hip_atomic_load(                                                 \
          &m2ws[((size_t)(wpar * 128 + (gX)) * 2 + (tid & 1)) * 128 +          \
                ((tid >> 1) - 128)],                                           \
          __ATOMIC_RELAXED, __HIP_MEMORY_SCOPE_AGENT);                         \
  }

#define WRITESTG(A1x, A2x, sm1, sm2, ssp, smk)                                 \
  {                                                                            \
    if (tid < 128)      A1x[tid] = (float)((smk >> (tid >> 1)) & 1ull);        \
    else if (tid < 384) A1x[tid] = sm1;                                        \
    if (tid < 256)      A2x[tid] = (float)((ssp >> ((tid >> 1) & 31)) & 1u);   \
    else                A2x[tid] = sm2;                                        \
  }

#define DO_CELLS(gX, g1x, g2x, sy1, me1, sy2, me2, fc)                         \
  if (tid < 64) {                                                              \
    const int hl = tid & 31, rr = tid >> 5;                                    \
    if (p < TSTEPS) {                                                          \
      float gi = bias1[hl]        + g1x[hl * 2 + rr];                          \
      float gf = bias1[32 + hl]   + g1x[(32 + hl) * 2 + rr];                   \
      float gg = bias1[64 + hl]   + g1x[(64 + hl) * 2 + rr];                   \
      float go = bias1[96 + hl]   + g1x[(96 + hl) * 2 + rr];                   \
      float rst = (me1 - thr1 > 0.0f) ? thr1 : 0.0f;                           \
      float cn = sigm(gf) * sy1 + sigm(gi) * tanhf(gg);                        \
      float mn = sigm(go) * tanhf(cn) - rst;                                   \
      sy1 = cn; me1 = mn;                                                      \
      __hip_atomic_store(                                                      \
          &m1ws[((size_t)((p & 1) * 128 + (gX)) * 2 + rr) * 128 +              \
                (q * 32 + hl)],                                                \
          mn, __ATOMIC_RELAXED, __HIP_MEMORY_SCOPE_AGENT);                     \
      unsigned long long bal = __ballot(mn - thr1 > 0.0f);                     \
      if (lane == 0)                                                           \
        __hip_atomic_store(&spkw[(size_t)((p & 1) * 128 + (gX)) * 8 + q],      \
                           (unsigned)(bal & 0xffffffffull),                    \
                           __ATOMIC_RELAXED, __HIP_MEMORY_SCOPE_AGENT);        \
      if (lane == 32)                                                          \
        __hip_atomic_store(&spkw[(size_t)((p & 1) * 128 + (gX)) * 8 + 4 + q],  \
                           (unsigned)(bal >> 32),                              \
                           __ATOMIC_RELAXED, __HIP_MEMORY_SCOPE_AGENT);        \
    }                                                                          \
    if (p >= 1) {                                                              \
      float gi = bias2[hl]        + g2x[hl * 2 + rr];                          \
      float gf = bias2[32 + hl]   + g2x[(32 + hl) * 2 + rr];                   \
      float gg = bias2[64 + hl]   + g2x[(64 + hl) * 2 + rr];                   \
      float go = bias2[96 + hl]   + g2x[(96 + hl) * 2 + rr];                   \
      float rst = (me2 - thr2 > 0.0f) ? thr2 : 0.0f;                           \
      float cn = sigm(gf) * sy2 + sigm(gi) * tanhf(gg);                        \
      float mn = sigm(go) * tanhf(cn) - rst;                                   \
      sy2 = cn; me2 = mn;                                                      \
      __hip_atomic_store(                                                      \
          &m2ws[((size_t)(((p + 1) & 1) * 128 + (gX)) * 2 + rr) * 128 +        \
                (q * 32 + hl)],                                                \
          mn, __ATOMIC_RELAXED, __HIP_MEMORY_SCOPE_AGENT);                     \
      fc += mn;                                                                \
    }                                                                          \
  }

#define FLAGX(gX, val)                                                         \
  if (tid == 0)                                                                \
    __hip_atomic_store(&flags[((size_t)(gX) * 4 + q) * 8], (unsigned)(val),    \
                       __ATOMIC_RELAXED, __HIP_MEMORY_SCOPE_AGENT);

#define POLLX(gX, val)                                                         \
  if (tid < 4) {                                                               \
    while (__hip_atomic_load(&flags[((size_t)(gX) * 4 + tid) * 8],             \
                             __ATOMIC_RELAXED, __HIP_MEMORY_SCOPE_AGENT) <     \
           (unsigned)(val))                                                    \
      __builtin_amdgcn_s_sleep(1);                                             \
  }

  // ---- prologue: issue both roles' phase-0 loads (buffers zeroed by k0) ----
  ISSUE(gA, 0, sm1a, sm2a, sspa, mka);
  ISSUE(gB, 0, sm1b, sm2b, sspb, mkb);
  __builtin_amdgcn_sched_barrier(0);

  for (int p = 0; p <= TSTEPS; ++p) {
    // ================= half A: group gA, phase p =================
    WRITESTG(A1a, A2a, sm1a, sm2a, sspa, mka);   // vmcnt waits land here
    __syncthreads();
    do_gemms(A1a, A2a, g1a, g2a, wr1, wr2, kq, j0);
    __syncthreads();
    DO_CELLS(gA, g1a, g2a, sy1a, me1a, sy2a, me2a, fca);
    __syncthreads();                             // drain publishes (vmcnt 0)
    if (p < TSTEPS) {
      FLAGX(gA, p + 1);
      POLLX(gA, p + 1);
      __syncthreads();
      ISSUE(gA, p + 1, sm1a, sm2a, sspa, mka);   // latency hides under half B
      __builtin_amdgcn_sched_barrier(0);
    }
    // ================= half B: group gB, phase p =================
    WRITESTG(A1b, A2b, sm1b, sm2b, sspb, mkb);
    __syncthreads();
    do_gemms(A1b, A2b, g1b, g2b, wr1, wr2, kq, j0);
    __syncthreads();
    DO_CELLS(gB, g1b, g2b, sy1b, me1b, sy2b, me2b, fcb);
    __syncthreads();
    if (p < TSTEPS) {
      FLAGX(gB, p + 1);
      POLLX(gB, p + 1);
      __syncthreads();
      ISSUE(gB, p + 1, sm1b, sm2b, sspb, mkb);   // latency hides under half A
      __builtin_amdgcn_sched_barrier(0);
    }
  }

  if (tid < 64) {
    const int hl = tid & 31, rr = tid >> 5;
    feat[((size_t)gA * 2 + rr) * 128 + q * 32 + hl] = fca * (1.0f / (float)TSTEPS);
    feat[((size_t)gB * 2 + rr) * 128 + q * 32 + hl] = fcb * (1.0f / (float)TSTEPS);
  }
#undef ISSUE
#undef WRITESTG
#undef DO_CELLS
#undef FLAGX
#undef POLLX
}

// ============================================================
// K3: head — gesture + (binary) domain_hidden -> domain
// ============================================================
__global__ __launch_bounds__(128) void k3_head(const float* __restrict__ feat,
    const float* __restrict__ gw, const float* __restrict__ gb,
    const float* __restrict__ d1w, const float* __restrict__ d1b,
    const float* __restrict__ thrdp,
    const float* __restrict__ d2w, const float* __restrict__ d2b,
    float* __restrict__ out) {
  __shared__ float fL[128];
  __shared__ float dh[64];
  const int b = blockIdx.x, t = threadIdx.x;
  fL[t] = feat[b * 128 + t];
  __syncthreads();
  if (t < 64) {
    float s = d1b[t];
    for (int k = 0; k < 128; ++k) s += d1w[t * 128 + k] * fL[k];
    dh[t] = (s - thrdp[0] > 0.0f) ? 1.0f : 0.0f;
  }
  __syncthreads();
  if (t < 8) {
    float s = gb[t];
    for (int k = 0; k < 128; ++k) s += gw[t * 128 + k] * fL[k];
    out[b * 8 + t] = s;
  }
  if (t >= 64 && t < 74) {
    const int o = t - 64;
    float s = d2b[o];
    for (int k = 0; k < 64; ++k) s += d2w[o * 64 + k] * dh[k];
    out[2048 + b * 10 + o] = s;
  }
}

// ============================================================
extern "C" void kernel_launch(void* const* d_in, const int* in_sizes, int n_in,
                              void* d_out, int out_size, void* d_ws, size_t ws_size,
                              hipStream_t stream) {
  const float* x      = (const float*)d_in[0];
  const float* conv_w = (const float*)d_in[1];
  const float* bn_g   = (const float*)d_in[2];
  const float* bn_b   = (const float*)d_in[3];
  const float* thrl1  = (const float*)d_in[4];
  const float* w_ih1  = (const float*)d_in[5];
  const float* w_hh1  = (const float*)d_in[6];
  const float* b_ih1  = (const float*)d_in[7];
  const float* b_hh1  = (const float*)d_in[8];
  const float* thr1   = (const float*)d_in[9];
  const float* w_ih2  = (const float*)d_in[10];
  const float* w_hh2  = (const float*)d_in[11];
  const float* b_ih2  = (const float*)d_in[12];
  const float* b_hh2  = (const float*)d_in[13];
  const float* thr2   = (const float*)d_in[14];
  const float* fc_g_w = (const float*)d_in[15];
  const float* fc_g_b = (const float*)d_in[16];
  const float* fc_d1w = (const float*)d_in[17];
  const float* fc_d1b = (const float*)d_in[18];
  const float* thrdom = (const float*)d_in[19];
  const float* fc_d2w = (const float*)d_in[20];
  const float* fc_d2b = (const float*)d_in[21];
  float* out = (float*)d_out;
  char* ws = (char*)d_ws;

  k0_zero<<<(ZERO_WORDS + 255) / 256, 256, 0, stream>>>((unsigned*)ws);
  k1_stats<<<dim3(NB, 9), 256, 0, stream>>>(x, conv_w, (float*)(ws + OFF_PART));
  k1b_reduce<<<1, 256, 0, stream>>>(bn_g, bn_b, (const float*)(ws + OFF_PART),
                                    (float*)(ws + OFF_AB));
  k2_spike<<<dim3(NB, 9), 256, 0, stream>>>(x, conv_w, thrl1,
                                            (const float*)(ws + OFF_AB),
                                            (unsigned long long*)(ws + OFF_MASK));
  kp_fused<<<256, 512, 0, stream>>>(ws, w_ih1, w_hh1, b_ih1, b_hh1, thr1,
                                    w_ih2, w_hh2, b_ih2, b_hh2, thr2);
  k3_head<<<NB, 128, 0, stream>>>((const float*)(ws + OFF_FEAT), fc_g_w, fc_g_b,
                                  fc_d1w, fc_d1b, thrdom, fc_d2w, fc_d2b, out);
}